// Round 7
// baseline (213.771 us; speedup 1.0000x reference)
//
#include <hip/hip_runtime.h>

// B=8, IN=256, HEADS=8, KEY=64, MEM=64, HEAD_DIM=64, OUT=256, HW=4096
// Folded form (two kernels; kernel boundary provides fold->main coherence):
//   A[(n,m)][c]  = sum_k key_p[n][k][m] * w_in[k*8+n][c]   (+ bb from b_in)
//   M[o][(n,m)]  = sum_d w_out[o][n*64+d] * memory[n][m][d]
//   logits = A @ x + bb -> softmax(64-row groups) -> out = M @ probs + b_out
// k-axis of GEMM2 permuted: col' = (n&1)*256 + (n>>1)*64 + m, so each wave's
// head pair splits into chunk0 (k' 0..255) / chunk1 (k' 256..511) -> 32 KB P buffer.

typedef _Float16 half8 __attribute__((ext_vector_type(8)));
typedef _Float16 half4 __attribute__((ext_vector_type(4)));
typedef _Float16 half2v __attribute__((ext_vector_type(2)));
typedef float float4v __attribute__((ext_vector_type(4)));

// ---------------- merged fold kernel ----------------
// blocks 0..511: A row (n*64+m); blocks 512..767: M row (o)
__global__ __launch_bounds__(256) void fold_all(
    const float* __restrict__ key_p, const float* __restrict__ w_in,
    const float* __restrict__ b_in, const float* __restrict__ w_out,
    const float* __restrict__ memory,
    _Float16* __restrict__ Aswz, _Float16* __restrict__ Mswz, float* __restrict__ bb)
{
    __shared__ float sv[512];
    __shared__ float red[64];
    const int blk = blockIdx.x;
    const int t = threadIdx.x;

    if (blk < 512) {
        const int row = blk, n = row >> 6, m = row & 63;
        if (t < 64) sv[t] = key_p[n * 4096 + t * 64 + m];   // key column
        __syncthreads();
        const int c = t;
        float v = 0.f;
        #pragma unroll 16
        for (int k = 0; k < 64; ++k)
            v = fmaf(sv[k], w_in[(k * 8 + n) * 256 + c], v);
        int R = row >> 4, s = c >> 5, i = c & 7;
        int l = (row & 15) + 16 * ((c >> 3) & 3);
        Aswz[(((R * 8 + s) * 64 + l) << 3) + i] = (_Float16)v;
        if (t < 64) red[t] = sv[t] * b_in[t * 8 + n];
        __syncthreads();
        if (t == 0) {
            float s2 = 0.f;
            for (int k = 0; k < 64; ++k) s2 += red[k];
            bb[row] = s2;
        }
    } else {
        const int o = blk - 512;
        sv[t]       = w_out[o * 512 + t];
        sv[256 + t] = w_out[o * 512 + 256 + t];
        __syncthreads();
        #pragma unroll
        for (int hh = 0; hh < 2; ++hh) {
            int col = t + hh * 256, n = col >> 6, m = col & 63;
            const float4* mrow = (const float4*)(memory + n * 4096 + m * 64);
            const float4* wrow = (const float4*)(sv + n * 64);
            float v = 0.f;
            #pragma unroll
            for (int qd = 0; qd < 16; ++qd) {
                float4 a = mrow[qd], w = wrow[qd];
                v += a.x * w.x + a.y * w.y + a.z * w.z + a.w * w.w;
            }
            // permuted column: col' = (n&1)*256 + (n>>1)*64 + m -> only s changes vs unpermuted
            int R2 = o >> 4, i = col & 7;
            int s = ((n & 1) << 3) + ((n >> 1) << 1) + (m >> 5);
            int l = (o & 15) + 16 * ((m >> 3) & 3);
            Mswz[(((R2 * 16 + s) * 64 + l) << 3) + i] = (_Float16)v;
        }
    }
}

// ---------------- main fused kernel ----------------
// 512 WGs x 256 threads; each WG: 64 positions. LDS: 34816 B -> 4 blocks/CU.
// Phase 1: Xs[p][c] fp16, stride 264 (33.8 KB). Phase 2: P chunk (256 k' x 64 pos, 32 KB),
// two GEMM2 passes. Phase 3: fp32 transpose buffer, stride 68 dwords (34.8 KB).
#define XS_STRIDE 264
#define SF_STRIDE 68

__global__ __launch_bounds__(256, 4) void fused_main(
    const float* __restrict__ x, const _Float16* __restrict__ Aswz,
    const float* __restrict__ bb, const _Float16* __restrict__ Mswz,
    const float* __restrict__ b_out, float* __restrict__ out)
{
    __shared__ _Float16 S[17408];   // 34816 B

    const int t  = threadIdx.x;
    const int w  = t >> 6;          // wave 0..3
    const int l  = t & 63;          // lane
    const int q  = l >> 4;          // quadrant 0..3
    const int lp = l & 15;
    const int wg  = blockIdx.x;
    const int b   = wg >> 6;
    const int hw0 = (wg & 63) * 64;
    const float* xb = x + (size_t)b * 256 * 4096 + hw0;

    // ---- stage Xs[p][c] fp16 (transposed); scatter reads absorbed by L3, LDS writes 2-way max ----
    #pragma unroll
    for (int i = 0; i < 8; ++i) {
        int u  = i * 256 + t;
        int cp = u & 127;           // channel pair (lane-fast)
        int qq = u >> 7;            // position quad 0..15
        int c0 = cp * 2, p4 = qq * 4;
        const float* px = xb + (size_t)c0 * 4096 + p4;
        float4 v0 = *(const float4*)(px);
        float4 v1 = *(const float4*)(px + 4096);
        *(half2v*)(&S[(p4 + 0) * XS_STRIDE + c0]) = half2v{(_Float16)v0.x, (_Float16)v1.x};
        *(half2v*)(&S[(p4 + 1) * XS_STRIDE + c0]) = half2v{(_Float16)v0.y, (_Float16)v1.y};
        *(half2v*)(&S[(p4 + 2) * XS_STRIDE + c0]) = half2v{(_Float16)v0.z, (_Float16)v1.z};
        *(half2v*)(&S[(p4 + 3) * XS_STRIDE + c0]) = half2v{(_Float16)v0.w, (_Float16)v1.w};
    }
    __syncthreads();

    // ---- GEMM1: logits[512 x 64] ----
    float4v acc[8][4];
    #pragma unroll
    for (int r = 0; r < 8; ++r)
        #pragma unroll
        for (int c = 0; c < 4; ++c) acc[r][c] = float4v{0.f, 0.f, 0.f, 0.f};

    const half8* Ag = (const half8*)Aswz;
    for (int s = 0; s < 8; ++s) {
        half8 bf[4];
        #pragma unroll
        for (int c = 0; c < 4; ++c)
            bf[c] = *(const half8*)(&S[(c * 16 + lp) * XS_STRIDE + s * 32 + q * 8]);
        half8 af[8];
        #pragma unroll
        for (int r = 0; r < 8; ++r)
            af[r] = Ag[((w * 8 + r) * 8 + s) * 64 + l];
        #pragma unroll
        for (int r = 0; r < 8; ++r)
            #pragma unroll
            for (int c = 0; c < 4; ++c)
                acc[r][c] = __builtin_amdgcn_mfma_f32_16x16x32_f16(af[r], bf[c], acc[r][c], 0, 0, 0);
    }

    // ---- bias ----
    #pragma unroll
    for (int r = 0; r < 8; ++r) {
        float4v bbv = *(const float4v*)(bb + w * 128 + r * 16 + q * 4);
        #pragma unroll
        for (int c = 0; c < 4; ++c)
            #pragma unroll
            for (int j = 0; j < 4; ++j) acc[r][c][j] += bbv[j];
    }

    __syncthreads();   // all waves done reading Xs (P chunk aliases it)

    // ---- softmax both heads; head A (r 0..3) -> LDS chunk, head B (r 4..7) -> packed regs ----
    // k' = (h)*256 + w*64 + m, m = rr*16 + q*4 + j; chunk-local s2c = w*2 + (rr>>1),
    // lane' = ((rr&1)*2 + (q>>1))*16 + lp, i0 = (q&1)*4
    half4 ph[4][4];
    #pragma unroll
    for (int h = 0; h < 2; ++h) {
        #pragma unroll
        for (int c = 0; c < 4; ++c) {
            float mx = -1e30f;
            #pragma unroll
            for (int rr = 0; rr < 4; ++rr) {
                int r = h * 4 + rr;
                #pragma unroll
                for (int j = 0; j < 4; ++j) mx = fmaxf(mx, acc[r][c][j]);
            }
            mx = fmaxf(mx, __shfl_xor(mx, 16, 64));
            mx = fmaxf(mx, __shfl_xor(mx, 32, 64));
            float sum = 0.f;
            #pragma unroll
            for (int rr = 0; rr < 4; ++rr) {
                int r = h * 4 + rr;
                #pragma unroll
                for (int j = 0; j < 4; ++j) {
                    float e = __expf(acc[r][c][j] - mx);
                    acc[r][c][j] = e;
                    sum += e;
                }
            }
            sum += __shfl_xor(sum, 16, 64);
            sum += __shfl_xor(sum, 32, 64);
            float inv = 1.f / sum;
            #pragma unroll
            for (int rr = 0; rr < 4; ++rr) {
                int r = h * 4 + rr;
                half4 pv = {(_Float16)(acc[r][c][0] * inv), (_Float16)(acc[r][c][1] * inv),
                            (_Float16)(acc[r][c][2] * inv), (_Float16)(acc[r][c][3] * inv)};
                if (h == 0) {
                    int s2c = w * 2 + (rr >> 1);
                    int lq = ((rr & 1) * 2 + (q >> 1)) * 16 + lp;
                    int i0 = (q & 1) * 4;
                    *(half4*)(&S[(((s2c * 4 + c) * 64) + lq) * 8 + i0]) = pv;
                } else {
                    ph[rr][c] = pv;
                }
            }
        }
    }
    __syncthreads();   // chunk 0 ready

    // ---- GEMM2: out[256 x 64] = M[256x512] @ P, two k-chunks ----
    float4v acc2[4][4];
    #pragma unroll
    for (int r = 0; r < 4; ++r)
        #pragma unroll
        for (int c = 0; c < 4; ++c) acc2[r][c] = float4v{0.f, 0.f, 0.f, 0.f};

    const half8* Mg = (const half8*)Mswz;
    for (int sc = 0; sc < 8; ++sc) {
        half8 bf2[4];
        #pragma unroll
        for (int c = 0; c < 4; ++c)
            bf2[c] = *(const half8*)(&S[(((sc * 4 + c) * 64) + l) * 8]);   // conflict-free b128
        half8 af2[4];
        #pragma unroll
        for (int r = 0; r < 4; ++r)
            af2[r] = Mg[((w * 4 + r) * 16 + sc) * 64 + l];
        #pragma unroll
        for (int r = 0; r < 4; ++r)
            #pragma unroll
            for (int c = 0; c < 4; ++c)
                acc2[r][c] = __builtin_amdgcn_mfma_f32_16x16x32_f16(af2[r], bf2[c], acc2[r][c], 0, 0, 0);
    }
    __syncthreads();   // chunk 0 reads done

    // ---- store head-B probs -> chunk 1 ----
    #pragma unroll
    for (int rr = 0; rr < 4; ++rr) {
        int s2c = w * 2 + (rr >> 1);
        int lq = ((rr & 1) * 2 + (q >> 1)) * 16 + lp;
        int i0 = (q & 1) * 4;
        #pragma unroll
        for (int c = 0; c < 4; ++c)
            *(half4*)(&S[(((s2c * 4 + c) * 64) + lq) * 8 + i0]) = ph[rr][c];
    }
    __syncthreads();   // chunk 1 ready

    for (int sc = 0; sc < 8; ++sc) {
        half8 bf2[4];
        #pragma unroll
        for (int c = 0; c < 4; ++c)
            bf2[c] = *(const half8*)(&S[(((sc * 4 + c) * 64) + l) * 8]);
        half8 af2[4];
        #pragma unroll
        for (int r = 0; r < 4; ++r)
            af2[r] = Mg[((w * 4 + r) * 16 + 8 + sc) * 64 + l];
        #pragma unroll
        for (int r = 0; r < 4; ++r)
            #pragma unroll
            for (int c = 0; c < 4; ++c)
                acc2[r][c] = __builtin_amdgcn_mfma_f32_16x16x32_f16(af2[r], bf2[c], acc2[r][c], 0, 0, 0);
    }

    // ---- epilogue: two-pass LDS transpose -> fully-coalesced float4 stores ----
    float* Sf = (float*)S;   // stride 68 dwords
    #pragma unroll
    for (int pass = 0; pass < 2; ++pass) {
        __syncthreads();   // prior S reads done
        if ((w >> 1) == pass) {
            int rbase = (w & 1) * 64;
            #pragma unroll
            for (int r = 0; r < 4; ++r)
                #pragma unroll
                for (int j = 0; j < 4; ++j)
                    #pragma unroll
                    for (int c = 0; c < 4; ++c)
                        Sf[(rbase + r * 16 + q * 4 + j) * SF_STRIDE + c * 16 + lp] = acc2[r][c][j];
        }
        __syncthreads();
        #pragma unroll
        for (int it = 0; it < 8; ++it) {
            int flat = it * 256 + t;    // 0..2047
            int row  = flat >> 4;       // 0..127 (local)
            int ch   = flat & 15;       // float4 chunk (position/4)
            float4 v = *(const float4*)(&Sf[row * SF_STRIDE + ch * 4]);
            int o = pass * 128 + row;
            float bo = b_out[o];
            v.x += bo; v.y += bo; v.z += bo; v.w += bo;
            *(float4*)(out + ((size_t)b * 256 + o) * 4096 + hw0 + ch * 4) = v;
        }
    }
}

extern "C" void kernel_launch(void* const* d_in, const int* in_sizes, int n_in,
                              void* d_out, int out_size, void* d_ws, size_t ws_size,
                              hipStream_t stream) {
    (void)in_sizes; (void)n_in; (void)ws_size; (void)out_size;
    const float* x      = (const float*)d_in[0];
    const float* key_p  = (const float*)d_in[1];
    const float* memory = (const float*)d_in[2];
    const float* w_in   = (const float*)d_in[3];
    const float* b_in   = (const float*)d_in[4];
    const float* w_out  = (const float*)d_in[5];
    const float* b_out  = (const float*)d_in[6];
    float* out = (float*)d_out;

    _Float16* Aswz = (_Float16*)d_ws;                       // 512*256 fp16 = 256 KB
    _Float16* Mswz = Aswz + 512 * 256;                      // 256*512 fp16 = 256 KB
    float*    bb   = (float*)(Mswz + 256 * 512);            // 512 fp32

    fold_all<<<768, 256, 0, stream>>>(key_p, w_in, b_in, w_out, memory, Aswz, Mswz, bb);
    fused_main<<<512, 256, 0, stream>>>(x, Aswz, bb, Mswz, b_out, out);
}

// Round 8
// 126.486 us; speedup vs baseline: 1.6901x; 1.6901x over previous
//
#include <hip/hip_runtime.h>

// B=8, IN=256, HEADS=8, KEY=64, MEM=64, HEAD_DIM=64, OUT=256, HW=4096
// Folded form (two kernels; kernel boundary provides fold->main coherence):
//   A[(n,m)][c]  = sum_k key_p[n][k][m] * w_in[k*8+n][c]   (+ bb from b_in)
//   M[o][(n,m)]  = sum_d w_out[o][n*64+d] * memory[n][m][d]
//   logits = A @ x + bb -> softmax(64-row groups) -> out = M @ probs + b_out
// Main kernel: 1024 WGs x 32 positions (half tile of R6) -> 64-reg accumulators,
// 36.9 KB LDS -> 4 blocks/CU (16 waves/CU) with NO spill (R7's failure mode).

typedef _Float16 half8 __attribute__((ext_vector_type(8)));
typedef _Float16 half4 __attribute__((ext_vector_type(4)));
typedef _Float16 half2v __attribute__((ext_vector_type(2)));
typedef float float4v __attribute__((ext_vector_type(4)));

// ---------------- merged fold kernel ----------------
// blocks 0..511: A row (n*64+m); blocks 512..767: M row (o)
__global__ __launch_bounds__(256) void fold_all(
    const float* __restrict__ key_p, const float* __restrict__ w_in,
    const float* __restrict__ b_in, const float* __restrict__ w_out,
    const float* __restrict__ memory,
    _Float16* __restrict__ Aswz, _Float16* __restrict__ Mswz, float* __restrict__ bb)
{
    __shared__ float sv[512];
    const int blk = blockIdx.x;
    const int t = threadIdx.x;

    if (blk < 512) {
        const int row = blk, n = row >> 6, m = row & 63;
        if (t < 64) sv[t] = key_p[n * 4096 + t * 64 + m];   // key column
        __syncthreads();
        const int c = t;
        float v = 0.f;
        #pragma unroll 16
        for (int k = 0; k < 64; ++k)
            v = fmaf(sv[k], w_in[(k * 8 + n) * 256 + c], v);
        int R = row >> 4, s = c >> 5, i = c & 7;
        int l = (row & 15) + 16 * ((c >> 3) & 3);
        Aswz[(((R * 8 + s) * 64 + l) << 3) + i] = (_Float16)v;
        // bb: wave-parallel reduction over k (threads 0..63)
        if (t < 64) {
            float rv = sv[t] * b_in[t * 8 + n];
            rv += __shfl_xor(rv, 32, 64);
            rv += __shfl_xor(rv, 16, 64);
            rv += __shfl_xor(rv, 8, 64);
            rv += __shfl_xor(rv, 4, 64);
            rv += __shfl_xor(rv, 2, 64);
            rv += __shfl_xor(rv, 1, 64);
            if (t == 0) bb[row] = rv;
        }
    } else {
        const int o = blk - 512;
        sv[t]       = w_out[o * 512 + t];
        sv[256 + t] = w_out[o * 512 + 256 + t];
        __syncthreads();
        #pragma unroll
        for (int hh = 0; hh < 2; ++hh) {
            int col = t + hh * 256, n = col >> 6, m = col & 63;
            const float4* mrow = (const float4*)(memory + n * 4096 + m * 64);
            const float4* wrow = (const float4*)(sv + n * 64);
            float v = 0.f;
            #pragma unroll
            for (int qd = 0; qd < 16; ++qd) {
                float4 a = mrow[qd], w = wrow[qd];
                v += a.x * w.x + a.y * w.y + a.z * w.z + a.w * w.w;
            }
            int R2 = o >> 4, s = col >> 5, i = col & 7;
            int l = (o & 15) + 16 * ((col >> 3) & 3);
            Mswz[(((R2 * 16 + s) * 64 + l) << 3) + i] = (_Float16)v;
        }
    }
}

// ---------------- main fused kernel ----------------
// 1024 WGs x 256 threads; each WG: 32 positions.
// LDS phases: Xs[p][c] fp16 stride 264 (16.9 KB) -> P full, B-frag layout
// (16 s-chunks x 2 ctiles x 64 lanes x 8 halves = 32 KB) -> Sf fp32 stride 36 (36.9 KB).
#define XS_STRIDE 264
#define SF_STRIDE 36

__global__ __launch_bounds__(256, 4) void fused_main(
    const float* __restrict__ x, const _Float16* __restrict__ Aswz,
    const float* __restrict__ bb, const _Float16* __restrict__ Mswz,
    const float* __restrict__ b_out, float* __restrict__ out)
{
    __shared__ _Float16 S[18432];   // 36864 B

    const int t  = threadIdx.x;
    const int w  = t >> 6;          // wave 0..3
    const int l  = t & 63;          // lane
    const int q  = l >> 4;          // quadrant 0..3
    const int lp = l & 15;
    const int wg  = blockIdx.x;     // 0..1023
    const int b   = wg >> 7;
    const int hw0 = (wg & 127) * 32;
    const float* xb = x + (size_t)b * 256 * 4096 + hw0;

    // ---- stage Xs[p][c] fp16 (transposed); 2-way-max LDS write conflicts ----
    #pragma unroll
    for (int i = 0; i < 4; ++i) {
        int u  = i * 256 + t;
        int cp = u & 127;           // channel pair (lane-fast)
        int qq = u >> 7;            // position quad 0..7
        int c0 = cp * 2, p4 = qq * 4;
        const float* px = xb + (size_t)c0 * 4096 + p4;
        float4 v0 = *(const float4*)(px);
        float4 v1 = *(const float4*)(px + 4096);
        *(half2v*)(&S[(p4 + 0) * XS_STRIDE + c0]) = half2v{(_Float16)v0.x, (_Float16)v1.x};
        *(half2v*)(&S[(p4 + 1) * XS_STRIDE + c0]) = half2v{(_Float16)v0.y, (_Float16)v1.y};
        *(half2v*)(&S[(p4 + 2) * XS_STRIDE + c0]) = half2v{(_Float16)v0.z, (_Float16)v1.z};
        *(half2v*)(&S[(p4 + 3) * XS_STRIDE + c0]) = half2v{(_Float16)v0.w, (_Float16)v1.w};
    }
    __syncthreads();

    // ---- GEMM1: logits[512 x 32]; wave w owns rows w*128..w*128+127 ----
    float4v acc[8][2];
    #pragma unroll
    for (int r = 0; r < 8; ++r)
        #pragma unroll
        for (int c = 0; c < 2; ++c) acc[r][c] = float4v{0.f, 0.f, 0.f, 0.f};

    const half8* Ag = (const half8*)Aswz;
    for (int s = 0; s < 8; ++s) {
        half8 bf[2];
        #pragma unroll
        for (int c = 0; c < 2; ++c)
            bf[c] = *(const half8*)(&S[(c * 16 + lp) * XS_STRIDE + s * 32 + q * 8]);
        #pragma unroll
        for (int rh = 0; rh < 2; ++rh) {        // r in chunks of 4: caps live af regs at 16
            half8 af4[4];
            #pragma unroll
            for (int rr = 0; rr < 4; ++rr)
                af4[rr] = Ag[((w * 8 + rh * 4 + rr) * 8 + s) * 64 + l];
            #pragma unroll
            for (int rr = 0; rr < 4; ++rr)
                #pragma unroll
                for (int c = 0; c < 2; ++c)
                    acc[rh * 4 + rr][c] =
                        __builtin_amdgcn_mfma_f32_16x16x32_f16(af4[rr], bf[c], acc[rh * 4 + rr][c], 0, 0, 0);
        }
    }

    // ---- bias ----
    #pragma unroll
    for (int r = 0; r < 8; ++r) {
        float4v bbv = *(const float4v*)(bb + w * 128 + r * 16 + q * 4);
        #pragma unroll
        for (int c = 0; c < 2; ++c)
            #pragma unroll
            for (int j = 0; j < 4; ++j) acc[r][c][j] += bbv[j];
    }

    __syncthreads();   // all waves done reading Xs (P aliases it)

    // ---- softmax (head h = rows w*128+h*64..+63) + store P in B-fragment layout ----
    // row = w*128 + h*64 + rr*16 + q*4 + j, col = c*16+lp
    // sc = w*4 + h*2 + (rr>>1); sub = (rr&1)*2 + (q>>1); i0 = (q&1)*4
    #pragma unroll
    for (int h = 0; h < 2; ++h) {
        #pragma unroll
        for (int c = 0; c < 2; ++c) {
            float mx = -1e30f;
            #pragma unroll
            for (int rr = 0; rr < 4; ++rr) {
                int r = h * 4 + rr;
                #pragma unroll
                for (int j = 0; j < 4; ++j) mx = fmaxf(mx, acc[r][c][j]);
            }
            mx = fmaxf(mx, __shfl_xor(mx, 16, 64));
            mx = fmaxf(mx, __shfl_xor(mx, 32, 64));
            float sum = 0.f;
            #pragma unroll
            for (int rr = 0; rr < 4; ++rr) {
                int r = h * 4 + rr;
                #pragma unroll
                for (int j = 0; j < 4; ++j) {
                    float e = __expf(acc[r][c][j] - mx);
                    acc[r][c][j] = e;
                    sum += e;
                }
            }
            sum += __shfl_xor(sum, 16, 64);
            sum += __shfl_xor(sum, 32, 64);
            float inv = 1.f / sum;
            #pragma unroll
            for (int rr = 0; rr < 4; ++rr) {
                int r = h * 4 + rr;
                int sc  = w * 4 + h * 2 + (rr >> 1);
                int sub = (rr & 1) * 2 + (q >> 1);
                int i0  = (q & 1) * 4;
                half4 pv = {(_Float16)(acc[r][c][0] * inv), (_Float16)(acc[r][c][1] * inv),
                            (_Float16)(acc[r][c][2] * inv), (_Float16)(acc[r][c][3] * inv)};
                *(half4*)(&S[(((sc * 2 + c) * 64) + sub * 16 + lp) * 8 + i0]) = pv;
            }
        }
    }
    __syncthreads();

    // ---- GEMM2: out[256 x 32] = M[256x512] @ P; wave w -> out rows w*64..w*64+63 ----
    float4v acc2[4][2];
    #pragma unroll
    for (int r = 0; r < 4; ++r)
        #pragma unroll
        for (int c = 0; c < 2; ++c) acc2[r][c] = float4v{0.f, 0.f, 0.f, 0.f};

    const half8* Mg = (const half8*)Mswz;
    for (int sc = 0; sc < 16; ++sc) {
        half8 bf2[2];
        #pragma unroll
        for (int c = 0; c < 2; ++c)
            bf2[c] = *(const half8*)(&S[(((sc * 2 + c) * 64) + l) * 8]);   // conflict-free b128
        half8 af2[4];
        #pragma unroll
        for (int r = 0; r < 4; ++r)
            af2[r] = Mg[((w * 4 + r) * 16 + sc) * 64 + l];
        #pragma unroll
        for (int r = 0; r < 4; ++r)
            #pragma unroll
            for (int c = 0; c < 2; ++c)
                acc2[r][c] = __builtin_amdgcn_mfma_f32_16x16x32_f16(af2[r], bf2[c], acc2[r][c], 0, 0, 0);
    }
    __syncthreads();   // P reads done; Sf aliases S

    // ---- epilogue: single-pass LDS transpose -> fully-coalesced float4 stores ----
    // acc2[r][c][j]: out row ob = w*64+r*16+q*4+j, position c*16+lp.
    float* Sf = (float*)S;   // stride 36 dwords, 16B-aligned rows
    #pragma unroll
    for (int r = 0; r < 4; ++r)
        #pragma unroll
        for (int j = 0; j < 4; ++j)
            #pragma unroll
            for (int c = 0; c < 2; ++c)
                Sf[(w * 64 + r * 16 + q * 4 + j) * SF_STRIDE + c * 16 + lp] = acc2[r][c][j];
    __syncthreads();
    #pragma unroll
    for (int it = 0; it < 8; ++it) {
        int flat = it * 256 + t;    // 0..2047
        int row  = flat >> 3;       // out channel 0..255
        int ch   = flat & 7;        // float4 chunk (position/4)
        float4 v = *(const float4*)(&Sf[row * SF_STRIDE + ch * 4]);
        float bo = b_out[row];
        v.x += bo; v.y += bo; v.z += bo; v.w += bo;
        *(float4*)(out + ((size_t)b * 256 + row) * 4096 + hw0 + ch * 4) = v;
    }
}

extern "C" void kernel_launch(void* const* d_in, const int* in_sizes, int n_in,
                              void* d_out, int out_size, void* d_ws, size_t ws_size,
                              hipStream_t stream) {
    (void)in_sizes; (void)n_in; (void)ws_size; (void)out_size;
    const float* x      = (const float*)d_in[0];
    const float* key_p  = (const float*)d_in[1];
    const float* memory = (const float*)d_in[2];
    const float* w_in   = (const float*)d_in[3];
    const float* b_in   = (const float*)d_in[4];
    const float* w_out  = (const float*)d_in[5];
    const float* b_out  = (const float*)d_in[6];
    float* out = (float*)d_out;

    _Float16* Aswz = (_Float16*)d_ws;                       // 512*256 fp16 = 256 KB
    _Float16* Mswz = Aswz + 512 * 256;                      // 256*512 fp16 = 256 KB
    float*    bb   = (float*)(Mswz + 256 * 512);            // 512 fp32

    fold_all<<<768, 256, 0, stream>>>(key_p, w_in, b_in, w_out, memory, Aswz, Mswz, bb);
    fused_main<<<1024, 256, 0, stream>>>(x, Aswz, bb, Mswz, b_out, out);
}